// Round 1
// baseline (460.033 us; speedup 1.0000x reference)
//
#include <hip/hip_runtime.h>

// 12-bit ripple-borrow subtractor on binary spike inputs (floats 0.0/1.0).
//
// R3: LDS-free streaming. One thread = one row.
//   - Each row is 48B (12 f32) = 3 x uint4, 16B-aligned (48*row % 16 == 0).
//     A thread loads its row with 3 dwordx4 loads at 48B lane stride. A
//     wave's 3 loads jointly cover one contiguous 3KB span, so every 64B
//     line is fetched once and fully used -> HBM traffic identical to the
//     fully-coalesced LDS-transpose version; only TA transactions rise.
//   - Removes R2's 72 scalar LDS ops + 2 barriers per thread. No LDS ->
//     no occupancy cap (expect 8 waves/SIMD) and no barrier-serialized
//     memory bursts; each wave keeps 6 independent loads in flight.
//   - Bit logic in integer domain: on {0.0f, 1.0f} inputs, bit 23 (exponent
//     LSB) of the IEEE-754 encoding is exactly the boolean value.

__global__ __launch_bounds__(256, 8) void Subtractor12Bit_kernel(
    const uint4* __restrict__ A4,    // [batch*3] uint4 (raw f32 bits)
    const uint4* __restrict__ B4,
    uint4* __restrict__ D4,          // diffs, [batch*3] uint4
    float* __restrict__ Borrow,      // [batch]
    int batch)
{
    const int row = blockIdx.x * 256 + threadIdx.x;
    if (row >= batch) return;
    const int base = row * 3;        // max 12.58M, fits int32

    const uint4 a0 = A4[base + 0];
    const uint4 a1 = A4[base + 1];
    const uint4 a2 = A4[base + 2];
    const uint4 b0 = B4[base + 0];
    const uint4 b1 = B4[base + 1];
    const uint4 b2 = B4[base + 2];

    // Pack 12 bits. Input index 0 = MSB (bit 11), index 11 = LSB (bit 0).
    const unsigned ua =
        (((a0.x >> 23) & 1u) << 11) | (((a0.y >> 23) & 1u) << 10) |
        (((a0.z >> 23) & 1u) <<  9) | (((a0.w >> 23) & 1u) <<  8) |
        (((a1.x >> 23) & 1u) <<  7) | (((a1.y >> 23) & 1u) <<  6) |
        (((a1.z >> 23) & 1u) <<  5) | (((a1.w >> 23) & 1u) <<  4) |
        (((a2.x >> 23) & 1u) <<  3) | (((a2.y >> 23) & 1u) <<  2) |
        (((a2.z >> 23) & 1u) <<  1) | (((a2.w >> 23) & 1u)      );
    const unsigned ub =
        (((b0.x >> 23) & 1u) << 11) | (((b0.y >> 23) & 1u) << 10) |
        (((b0.z >> 23) & 1u) <<  9) | (((b0.w >> 23) & 1u) <<  8) |
        (((b1.x >> 23) & 1u) <<  7) | (((b1.y >> 23) & 1u) <<  6) |
        (((b1.z >> 23) & 1u) <<  5) | (((b1.w >> 23) & 1u) <<  4) |
        (((b2.x >> 23) & 1u) <<  3) | (((b2.y >> 23) & 1u) <<  2) |
        (((b2.z >> 23) & 1u) <<  1) | (((b2.w >> 23) & 1u)      );

    const unsigned diff = (ua - ub) & 0xFFFu;

    Borrow[row] = (ub > ua) ? 1.0f : 0.0f;   // coalesced 4B/lane

    // Unpack: bit -> 0x3F800000 (1.0f) or 0, via mask = 0 - bit.
    const unsigned ONE = 0x3F800000u;
    uint4 d0, d1, d2;
    d0.x = ONE & (0u - ((diff >> 11) & 1u));
    d0.y = ONE & (0u - ((diff >> 10) & 1u));
    d0.z = ONE & (0u - ((diff >>  9) & 1u));
    d0.w = ONE & (0u - ((diff >>  8) & 1u));
    d1.x = ONE & (0u - ((diff >>  7) & 1u));
    d1.y = ONE & (0u - ((diff >>  6) & 1u));
    d1.z = ONE & (0u - ((diff >>  5) & 1u));
    d1.w = ONE & (0u - ((diff >>  4) & 1u));
    d2.x = ONE & (0u - ((diff >>  3) & 1u));
    d2.y = ONE & (0u - ((diff >>  2) & 1u));
    d2.z = ONE & (0u - ((diff >>  1) & 1u));
    d2.w = ONE & (0u - ( diff        & 1u));

    D4[base + 0] = d0;
    D4[base + 1] = d1;
    D4[base + 2] = d2;
}

extern "C" void kernel_launch(void* const* d_in, const int* in_sizes, int n_in,
                              void* d_out, int out_size, void* d_ws, size_t ws_size,
                              hipStream_t stream) {
    const float* A = (const float*)d_in[0];
    const float* B = (const float*)d_in[1];
    float* out = (float*)d_out;

    const int batch = in_sizes[0] / 12;             // 4,194,304
    float* diffs = out;                             // [batch*12]
    float* borrow = out + (size_t)batch * 12;       // [batch]

    const int grid = (batch + 255) / 256;           // 16384
    Subtractor12Bit_kernel<<<grid, 256, 0, stream>>>(
        (const uint4*)A, (const uint4*)B, (uint4*)diffs, borrow, batch);
}